// Round 19
// baseline (205.602 us; speedup 1.0000x reference)
//
#include <hip/hip_runtime.h>

// ---------------------------------------------------------------------------
// qkv = x@W_attn; RoPE(q,k); flash-attn; y@W_proj
// B=2, T=2048, C=1024, H=16, HD=64.  I/O fp32; internal tensors bf16.
//
// R30 (R29 measured 199.56us; attn per-dispatch REGRESSED 48.6->50.5 because
// the A/B chains were sequential — compiler couldn't interleave across the
// softmax/Ps section.  Fix: MANUAL fusion):
//  * attn fused dual-tile body (kt2 < nktB): QK^T reads ka once for BOTH
//    tiles (halves K ds_reads); softmax max/shfl/exp loops interleave the
//    two independent chains in adjacent instructions; PV reads va once for
//    both O accumulations (halves V ds_reads).  PsB gets its own LDS buffer
//    (67KB/block total, x2 = 134 <= 160 -> still 2 blocks/CU).
//  * A-only tail (kt2 >= nktB) = measured R26 body verbatim.
//  * per-chain math identical to R29 (passed); ~150 VGPR < 256 cap.
//  * everything else byte-identical to R29 (gemm1 128x128, gemm2 R18-form,
//    rope table, merged launches).
// ---------------------------------------------------------------------------

typedef __attribute__((ext_vector_type(8))) short short8;   // 8 bf16 = 4 VGPRs
typedef __attribute__((ext_vector_type(4))) float floatx4;  // MFMA C/D frag

__device__ __forceinline__ ushort f2bf(float f) {
    unsigned x = __float_as_uint(f);
    x += 0x7fffu + ((x >> 16) & 1u);   // round-to-nearest-even
    return (ushort)(x >> 16);
}
__device__ __forceinline__ float bf2f(ushort u) {
    return __uint_as_float(((unsigned)u) << 16);
}
__device__ __forceinline__ float exp2fast(float x) {   // 2^x, raw v_exp_f32
    float r;
    asm("v_exp_f32 %0, %1" : "=v"(r) : "v"(x));
    return r;
}
__device__ __forceinline__ unsigned cvtpk_bf16(float lo, float hi) {
    unsigned r;                                        // [bf16(hi)|bf16(lo)]
    asm("v_cvt_pk_bf16_f32 %0, %1, %2" : "=v"(r) : "v"(lo), "v"(hi));
    return r;
}

#define MFMA16(a, b, c) __builtin_amdgcn_mfma_f32_16x16x32_bf16((a), (b), (c), 0, 0, 0)

// async global->LDS, 16 bytes per lane.  LDS dest must be wave-uniform base;
// HW writes base + lane*16.  Global src is per-lane.
__device__ __forceinline__ void glds16(const ushort* g, ushort* l) {
    __builtin_amdgcn_global_load_lds(
        (const __attribute__((address_space(1))) unsigned int*)g,
        (__attribute__((address_space(3))) unsigned int*)l, 16, 0, 0);
}

// ---------------------------------------------------------------------------
// Transpose + cvt: src f32 [R][C] -> dst bf16 [C][R].  32x32 tiles via LDS.
// ---------------------------------------------------------------------------
__global__ __launch_bounds__(256) void tp_k(const float* __restrict__ src,
                                            ushort* __restrict__ dst,
                                            int R, int C) {
    __shared__ ushort t[32][34];
    const int c0 = blockIdx.x * 32, r0 = blockIdx.y * 32;
    const int tr = threadIdx.x >> 5, tc = threadIdx.x & 31;
#pragma unroll
    for (int j = 0; j < 4; j++)
        t[tr + j * 8][tc] = f2bf(src[(size_t)(r0 + tr + j * 8) * C + c0 + tc]);
    __syncthreads();
#pragma unroll
    for (int j = 0; j < 4; j++)
        dst[(size_t)(c0 + tr + j * 8) * R + r0 + tc] = t[tc][tr + j * 8];
}

// ---------------------------------------------------------------------------
// cvt: f32 -> bf16, 4 elems/thread.
// ---------------------------------------------------------------------------
__global__ __launch_bounds__(256) void cvt_k(const float* __restrict__ src,
                                             ushort* __restrict__ dst) {
    const size_t i = ((size_t)blockIdx.x * 256 + threadIdx.x) * 4;
    float4 t4 = *(const float4*)&src[i];
    *(ushort4*)&dst[i] = make_ushort4(f2bf(t4.x), f2bf(t4.y), f2bf(t4.z), f2bf(t4.w));
}

// ---------------------------------------------------------------------------
// trig table: tab[t][j] = (cos(t * 10000^(-j/32)), sin(...)), f64 math.
// ---------------------------------------------------------------------------
__global__ __launch_bounds__(256) void trig_k(float2* __restrict__ tab) {
    const int idx = blockIdx.x * 256 + threadIdx.x;   // [0, 65536)
    const int t = idx >> 5, j = idx & 31;
    const double inv = pow(10000.0, -(double)j / 32.0);
    const double ang = (double)t * inv;
    tab[idx] = make_float2((float)cos(ang), (float)sin(ang));
}

// ---------------------------------------------------------------------------
// GEMM1: qkv = xb[2048][1024](bf16) @ WaT^T (Bt bf16 [3072][1024])
// R27: 128x128 tile (grid 24x16xZ), BK=64, glds16, swizzled LDS.
// ---------------------------------------------------------------------------
__global__ __launch_bounds__(256, 3) void gemm1_qkv_k(const ushort* __restrict__ Ab,
                                                      const ushort* __restrict__ Bt,
                                                      ushort* __restrict__ qb,
                                                      ushort* __restrict__ kb,
                                                      ushort* __restrict__ vtb) {
    __shared__ __align__(16) ushort As[128 * 64];  // 16 KB, linear+swizzled
    __shared__ __align__(16) ushort Bs[128 * 64];  // 16 KB
    const size_t boff = (size_t)blockIdx.z * (2048u * 1024u);
    Ab += boff; qb += boff; kb += boff; vtb += boff;
    const int tid = threadIdx.x;
    const int m0 = blockIdx.y * 128, n0 = blockIdx.x * 128;
    const int w = tid >> 6, lane = tid & 63, quad = lane >> 4, l16 = lane & 15;
    const int wr = w >> 1, wc = w & 1;
    const int K = 1024;
    const int srow = lane >> 3, sslot = lane & 7;  // staging sub-row / slot

    floatx4 acc[4][4];
#pragma unroll
    for (int mt = 0; mt < 4; mt++)
#pragma unroll
        for (int nt = 0; nt < 4; nt++) acc[mt][nt] = (floatx4){0.f, 0.f, 0.f, 0.f};

    for (int k0 = 0; k0 < K; k0 += 64) {
        __syncthreads();   // all waves done reading prev tile
#pragma unroll
        for (int jj = 0; jj < 4; jj++) {
            const int reg = jj * 4 + w;
            const int row = reg * 8 + srow;
            const int cs = sslot ^ (row & 7);
            glds16(&Ab[(size_t)(m0 + row) * K + k0 + cs * 8], &As[reg * 512]);
        }
#pragma unroll
        for (int jj = 0; jj < 4; jj++) {
            const int reg = jj * 4 + w;
            const int row = reg * 8 + srow;
            const int cs = sslot ^ (row & 7);
            glds16(&Bt[(size_t)(n0 + row) * K + k0 + cs * 8], &Bs[reg * 512]);
        }
        __syncthreads();   // compiler drains vmcnt(0) before barrier

#pragma unroll
        for (int kk = 0; kk < 2; kk++) {
            short8 af[4], bfr[4];
#pragma unroll
            for (int mt = 0; mt < 4; mt++) {
                const int row = wr * 64 + mt * 16 + l16;
                const int slot = ((kk << 2) | quad) ^ (row & 7);
                af[mt] = *(short8*)&As[row * 64 + slot * 8];
            }
#pragma unroll
            for (int nt = 0; nt < 4; nt++) {
                const int row = wc * 64 + nt * 16 + l16;
                const int slot = ((kk << 2) | quad) ^ (row & 7);
                bfr[nt] = *(short8*)&Bs[row * 64 + slot * 8];
            }
#pragma unroll
            for (int mt = 0; mt < 4; mt++)
#pragma unroll
                for (int nt = 0; nt < 4; nt++) acc[mt][nt] = MFMA16(af[mt], bfr[nt], acc[mt][nt]);
        }
    }

    // Epilogue [R5-R14 verified 128x128 formulas]
#pragma unroll
    for (int nt = 0; nt < 4; nt++) {
        const int n = n0 + wc * 64 + nt * 16 + l16;
        const int seg = n >> 10;          // 0=q 1=k 2=v
        const int cn = n & 1023;
        const int h = cn >> 6, d = cn & 63;
#pragma unroll
        for (int mt = 0; mt < 4; mt++) {
#pragma unroll
            for (int r = 0; r < 4; r++) {
                const int t = m0 + wr * 64 + mt * 16 + quad * 4 + r;
                const ushort v = f2bf(acc[mt][nt][r]);
                if (seg == 0)      qb[((size_t)h * 2048 + t) * 64 + d] = v;
                else if (seg == 1) kb[((size_t)h * 2048 + t) * 64 + d] = v;
                else               vtb[((size_t)h * 64 + d) * 2048 + t] = v;
            }
        }
    }
}

// ---------------------------------------------------------------------------
// RoPE (roll variant), table-based trig.
// ---------------------------------------------------------------------------
__global__ __launch_bounds__(256) void rope_k(ushort* __restrict__ q,
                                              ushort* __restrict__ k,
                                              const float2* __restrict__ tab) {
    const int wid = blockIdx.x * 4 + (threadIdx.x >> 6);  // row
    const int lane = threadIdx.x & 63;
    const int t = wid & 2047;
    const float2 cs = tab[t * 32 + (lane & 31)];
    const float c = cs.x;
    const float s = cs.y;
    const size_t base = (size_t)wid * 64;

    float qv = bf2f(q[base + lane]);
    float qp = __shfl(qv, (lane + 63) & 63, 64);
    q[base + lane] = f2bf(qv * c + qp * s);

    float kv = bf2f(k[base + lane]);
    float kp = __shfl(kv, (lane + 63) & 63, 64);
    k[base + lane] = f2bf(kv * c + kp * s);
}

// ---------------------------------------------------------------------------
// Flash attention (causal), transposed form.
// R21: KVBLK=128 + glds16 staging + exact-skip + setprio.
// R26: mask-skip, exp2-domain softmax, cvt_pk P->bf16.
// R29: two q-tiles per block (qtA=31-g, qtB=g, same head), shared staging.
// R30: FUSED dual-tile body — shared ka/va LDS reads feed both chains;
//      softmax chains interleaved in the same loops; PsB separate buffer.
// ---------------------------------------------------------------------------
__global__ __launch_bounds__(256, 2) void attn_k(const ushort* __restrict__ q,
                                                 const ushort* __restrict__ k,
                                                 const ushort* __restrict__ vt,
                                                 ushort* __restrict__ y) {
    __shared__ __align__(16) ushort Ks[128 * 64];    // [key][d]  16 KB swz
    __shared__ __align__(16) ushort Vs[64 * 128];    // [d][key]  16 KB swz
    __shared__ __align__(16) ushort PsA[4][16][136]; // per-wave P^T (tile A)
    __shared__ __align__(16) ushort PsB[4][16][136]; // per-wave P^T (tile B)

    const int bid = blockIdx.x;
    const int b = bid >> 8;            // batch (0 under fallback grid 256)
    const int r8 = bid & 255;
    const int g = r8 >> 4;             // pair index 0..15
    const int h = r8 & 15;
    const int qtA = 31 - g, qtB = g;
    const size_t boff = (size_t)b * (2048u * 1024u);
    q += boff; k += boff; vt += boff; y += boff;
    const int tid = threadIdx.x, w = tid >> 6, lane = tid & 63;
    const int quad = lane >> 4, l16 = lane & 15;
    const int srow8 = lane >> 3, sslot8 = lane & 7;   // K staging (8 rows/KB)
    const int srow4 = lane >> 4, sslot16 = lane & 15; // V staging (4 rows/KB)

    const int qrowA = qtA * 64 + w * 16 + l16;
    const int qrowB = qtB * 64 + w * 16 + l16;
    const int wrow0A = qtA * 64 + w * 16;
    const int wrow0B = qtB * 64 + w * 16;
    const int nktA = (qtA >> 1) + 1;   // B: nktB <= nktA always
    const int nktB = (qtB >> 1) + 1;
    const float SC = 0.125f * 1.44269504f;  // score scale folded with log2(e)

    short8 qaA0, qaA1, qaB0, qaB1;
    {
        const ushort* qp = q + ((size_t)h * 2048 + qrowA) * 64 + quad * 8;
        qaA0 = *(const short8*)(qp);
        qaA1 = *(const short8*)(qp + 32);
        const ushort* qp2 = q + ((size_t)h * 2048 + qrowB) * 64 + quad * 8;
        qaB0 = *(const short8*)(qp2);
        qaB1 = *(const short8*)(qp2 + 32);
    }

    floatx4 OA[4], OB[4];
#pragma unroll
    for (int dt = 0; dt < 4; dt++) {
        OA[dt] = (floatx4){0.f, 0.f, 0.f, 0.f};
        OB[dt] = (floatx4){0.f, 0.f, 0.f, 0.f};
    }
    float MA = -30000.f, LA = 0.f, MB = -30000.f, LB = 0.f;

    for (int kt2 = 0; kt2 < nktA; kt2++) {
        const int kbase = kt2 * 128;
        __syncthreads();   // all waves done reading prev tile's LDS
#pragma unroll
        for (int jj = 0; jj < 4; jj++) {
            const int reg = jj * 4 + w;
            const int row = reg * 8 + srow8;
            const int cs = sslot8 ^ (row & 7);
            glds16(&k[((size_t)h * 2048 + kbase + row) * 64 + cs * 8], &Ks[reg * 512]);
        }
#pragma unroll
        for (int jj = 0; jj < 4; jj++) {
            const int reg = jj * 4 + w;
            const int row = reg * 4 + srow4;
            const int cs = sslot16 ^ (row & 15);
            glds16(&vt[((size_t)h * 64 + row) * 2048 + kbase + cs * 8], &Vs[reg * 512]);
        }
        __syncthreads();   // staging complete (vmcnt(0) drained at barrier)

        if (kt2 < nktB) {
            // ================= FUSED A+B body =================
            floatx4 sA[8], sB[8];
            __builtin_amdgcn_s_setprio(1);
#pragma unroll
            for (int nt = 0; nt < 8; nt++) {
                const int row = nt * 16 + l16;
                short8 ka0 = *(short8*)&Ks[row * 64 + ((quad ^ (row & 7)) * 8)];
                short8 ka1 = *(short8*)&Ks[row * 64 + (((4 | quad) ^ (row & 7)) * 8)];
                floatx4 zA = (floatx4){0.f, 0.f, 0.f, 0.f};
                floatx4 zB = (floatx4){0.f, 0.f, 0.f, 0.f};
                zA = MFMA16(ka0, qaA0, zA);
                zB = MFMA16(ka0, qaB0, zB);
                zA = MFMA16(ka1, qaA1, zA);
                zB = MFMA16(ka1, qaB1, zB);
                sA[nt] = zA;
                sB[nt] = zB;
            }
            __builtin_amdgcn_s_setprio(0);

            // scale (+mask) A
            if (kbase + 127 <= wrow0A) {
#pragma unroll
                for (int nt = 0; nt < 8; nt++)
#pragma unroll
                    for (int r = 0; r < 4; r++) sA[nt][r] *= SC;
            } else {
#pragma unroll
                for (int nt = 0; nt < 8; nt++)
#pragma unroll
                    for (int r = 0; r < 4; r++) {
                        const int kidx = kbase + nt * 16 + quad * 4 + r;
                        const float vv = sA[nt][r] * SC;
                        sA[nt][r] = (kidx > qrowA) ? -30000.f : vv;
                    }
            }
            // scale (+mask) B
            if (kbase + 127 <= wrow0B) {
#pragma unroll
                for (int nt = 0; nt < 8; nt++)
#pragma unroll
                    for (int r = 0; r < 4; r++) sB[nt][r] *= SC;
            } else {
#pragma unroll
                for (int nt = 0; nt < 8; nt++)
#pragma unroll
                    for (int r = 0; r < 4; r++) {
                        const int kidx = kbase + nt * 16 + quad * 4 + r;
                        const float vv = sB[nt][r] * SC;
                        sB[nt][r] = (kidx > qrowB) ? -30000.f : vv;
                    }
            }

            // interleaved max trees
            float mrA[8], mrB[8];
#pragma unroll
            for (int nt = 0; nt < 8; nt++) {
                mrA[nt] = fmaxf(fmaxf(sA[nt][0], sA[nt][1]), fmaxf(sA[nt][2], sA[nt][3]));
                mrB[nt] = fmaxf(fmaxf(sB[nt][0], sB[nt][1]), fmaxf(sB[nt][2], sB[nt][3]));
            }
            float mxA = fmaxf(fmaxf(fmaxf(mrA[0], mrA[1]), fmaxf(mrA[2], mrA[3])),
                              fmaxf(fmaxf(mrA[4], mrA[5]), fmaxf(mrA[6], mrA[7])));
            float mxB = fmaxf(fmaxf(fmaxf(mrB[0], mrB[1]), fmaxf(mrB[2], mrB[3])),
                              fmaxf(fmaxf(mrB[4], mrB[5]), fmaxf(mrB[6], mrB[7])));
            mxA = fmaxf(mxA, __shfl_xor(mxA, 16, 64));
            mxB = fmaxf(mxB, __shfl_xor(mxB, 16, 64));
            mxA = fmaxf(mxA, __shfl_xor(mxA, 32, 64));
            mxB = fmaxf(mxB, __shfl_xor(mxB, 32, 64));

            if (!__all(mxA <= MA)) {
                const float Mn = fmaxf(MA, mxA);
                const float alpha = exp2fast(MA - Mn);
                LA *= alpha;
#pragma unroll
                for (int dt = 0; dt < 4; dt++) OA[dt] *= alpha;
                MA = Mn;
            }
            if (!__all(mxB <= MB)) {
                const float Mn = fmaxf(MB, mxB);
                const float alpha = exp2fast(MB - Mn);
                LB *= alpha;
#pragma unroll
                for (int dt = 0; dt < 4; dt++) OB[dt] *= alpha;
                MB = Mn;
            }

            // interleaved exp
            float sumA = 0.f, sumB = 0.f;
#pragma unroll
            for (int nt = 0; nt < 8; nt++)
#pragma unroll
                for (int r = 0; r < 4; r++) {
                    const float pA = exp2fast(sA[nt][r] - MA);
                    const float pB = exp2fast(sB[nt][r] - MB);
                    sA[nt][r] = pA;
                    sB[nt][r] = pB;
                    sumA += pA;
                    sumB += pB;
                }
            sumA += __shfl_xor(sumA, 16, 64);
            sumB += __shfl_xor(sumB, 16, 64);
            sumA += __shfl_xor(sumA, 32, 64);
            sumB += __shfl_xor(sumB, 32, 64);
            LA += sumA;
            LB += sumB;

            // P -> bf16 into separate Ps buffers
#pragma unroll
            for (int nt = 0; nt < 8; nt++) {
                uint2 pkA, pkB;
                pkA.x = cvtpk_bf16(sA[nt][0], sA[nt][1]);
                pkA.y = cvtpk_bf16(sA[nt][2], sA[nt][3]);
                pkB.x = cvtpk_bf16(sB[nt][0], sB[nt][1]);
                pkB.y = cvtpk_bf16(sB[nt][2], sB[nt][3]);
                *(uint2*)&PsA[w][l16][nt * 16 + quad * 4] = pkA;
                *(uint2*)&PsB[w][l16][nt * 16 + quad * 4] = pkB;
            }
            short8 pbA[4], pbB[4];
#pragma unroll
            for (int ks = 0; ks < 4; ks++) {
                pbA[ks] = *(short8*)&PsA[w][l16][ks * 32 + quad * 8];
                pbB[ks] = *(short8*)&PsB[w][l16][ks * 32 + quad * 8];
            }
            // fused PV: va read once feeds both accumulations
            __builtin_amdgcn_s_setprio(1);
#pragma unroll
            for (int dt = 0; dt < 4; dt++) {
                const int row = dt * 16 + l16;
#pragma unroll
                for (int ks = 0; ks < 4; ks++) {
                    const int cc = (ks * 4 + quad) ^ (row & 15);
                    short8 va = *(short8*)&Vs[row * 128 + cc * 8];
                    OA[dt] = MFMA16(va, pbA[ks], OA[dt]);
                    OB[dt] = MFMA16(va, pbB[ks], OB[dt]);
                }
            }
            __builtin_amdgcn_s_setprio(0);
        } else {
            // ================= A-only body (R26 form) =================
            floatx4 s[8];
            __builtin_amdgcn_s_setprio(1);
#pragma unroll
            for (int nt = 0; nt < 8; nt++) {
                const int row = nt * 16 + l16;
                short8 ka0 = *(short8*)&Ks[row * 64 + ((quad ^ (row & 7)) * 8)];
                short8 ka1 = *(short8*)&Ks[row * 64 + (((4 | quad) ^ (row & 7)) * 8)];
                floatx4 z = (floatx4){0.f, 0.f, 0.f, 0.f};
                z = MFMA16(ka0, qaA0, z);
                z = MFMA16(ka1, qaA1, z);
                s[nt] = z;
            }
            __builtin_amdgcn_s_setprio(0);

            if (kbase + 127 <= wrow0A) {
#pragma unroll
                for (int nt = 0; nt < 8; nt++)
#pragma unroll
                    for (int r = 0; r < 4; r++) s[nt][r] *= SC;
            } else {
#pragma unroll
                for (int nt = 0; nt < 8; nt++)
#pragma unroll
                    for (int r = 0; r < 4; r++) {
                        const int kidx = kbase + nt * 16 + quad * 4 + r;
                        const float vv = s[nt][r] * SC;
                        s[nt][r] = (kidx > qrowA) ? -30000.f : vv;
                    }
            }

            float mr[8];
#pragma unroll
            for (int nt = 0; nt < 8; nt++)
                mr[nt] = fmaxf(fmaxf(s[nt][0], s[nt][1]), fmaxf(s[nt][2], s[nt][3]));
            float mx = fmaxf(fmaxf(fmaxf(mr[0], mr[1]), fmaxf(mr[2], mr[3])),
                             fmaxf(fmaxf(mr[4], mr[5]), fmaxf(mr[6], mr[7])));
            mx = fmaxf(mx, __shfl_xor(mx, 16, 64));
            mx = fmaxf(mx, __shfl_xor(mx, 32, 64));

            if (!__all(mx <= MA)) {
                const float Mn = fmaxf(MA, mx);
                const float alpha = exp2fast(MA - Mn);
                LA *= alpha;
#pragma unroll
                for (int dt = 0; dt < 4; dt++) OA[dt] *= alpha;
                MA = Mn;
            }

            float sum = 0.f;
#pragma unroll
            for (int nt = 0; nt < 8; nt++)
#pragma unroll
                for (int r = 0; r < 4; r++) {
                    const float pv = exp2fast(s[nt][r] - MA);
                    s[nt][r] = pv;
                    sum += pv;
                }
            sum += __shfl_xor(sum, 16, 64);
            sum += __shfl_xor(sum, 32, 64);
            LA += sum;

#pragma unroll
            for (int nt = 0; nt < 8; nt++) {
                uint2 pk2;
                pk2.x = cvtpk_bf16(s[nt][0], s[nt][1]);
                pk2.y = cvtpk_bf16(s[nt][2], s[nt][3]);
                *(uint2*)&PsA[w][l16][nt * 16 + quad * 4] = pk2;
            }
            short8 pb[4];
#pragma unroll
            for (int ks = 0; ks < 4; ks++)
                pb[ks] = *(short8*)&PsA[w][l16][ks * 32 + quad * 8];
            __builtin_amdgcn_s_setprio(1);
#pragma unroll
            for (int dt = 0; dt < 4; dt++) {
                const int row = dt * 16 + l16;
#pragma unroll
                for (int ks = 0; ks < 4; ks++) {
                    const int cc = (ks * 4 + quad) ^ (row & 15);
                    short8 va = *(short8*)&Vs[row * 128 + cc * 8];
                    OA[dt] = MFMA16(va, pb[ks], OA[dt]);
                }
            }
            __builtin_amdgcn_s_setprio(0);
        }
    }

    {
        const float rl = 1.0f / LA;
#pragma unroll
        for (int dt = 0; dt < 4; dt++) {
            ushort4 o4 = make_ushort4(f2bf(OA[dt][0] * rl), f2bf(OA[dt][1] * rl),
                                      f2bf(OA[dt][2] * rl), f2bf(OA[dt][3] * rl));
            *(ushort4*)&y[(size_t)qrowA * 1024 + h * 64 + dt * 16 + quad * 4] = o4;
        }
    }
    {
        const float rl = 1.0f / LB;
#pragma unroll
        for (int dt = 0; dt < 4; dt++) {
            ushort4 o4 = make_ushort4(f2bf(OB[dt][0] * rl), f2bf(OB[dt][1] * rl),
                                      f2bf(OB[dt][2] * rl), f2bf(OB[dt][3] * rl));
            *(ushort4*)&y[(size_t)qrowB * 1024 + h * 64 + dt * 16 + quad * 4] = o4;
        }
    }
}

// ---------------------------------------------------------------------------
// GEMM2: out(f32) = y[2048][1024](bf16) @ WpT^T (bf16 [1024][1024])
// R15/R18 form: 64x64 tile, BK=64, glds16, swizzled LDS.
// ---------------------------------------------------------------------------
__global__ __launch_bounds__(256, 2) void gemm2_proj_k(const ushort* __restrict__ Y,
                                                       const ushort* __restrict__ Bt,
                                                       float* __restrict__ out) {
    __shared__ __align__(16) ushort As[64 * 64];   // 8 KB, linear+swizzled
    __shared__ __align__(16) ushort Bs[64 * 64];   // 8 KB
    const size_t boff = (size_t)blockIdx.z * (2048u * 1024u);
    Y += boff; out += boff;
    const int tid = threadIdx.x;
    const int m0 = blockIdx.y * 64, n0 = blockIdx.x * 64;
    const int w = tid >> 6, lane = tid & 63, quad = lane >> 4, l16 = lane & 15;
    const int wr = w >> 1, wc = w & 1;
    const int K = 1024;
    const int srow = lane >> 3, sslot = lane & 7;

    floatx4 acc[2][2];
#pragma unroll
    for (int mt = 0; mt < 2; mt++)
#pragma unroll
        for (int nt = 0; nt < 2; nt++) acc[mt][nt] = (floatx4){0.f, 0.f, 0.f, 0.f};

    for (int k0 = 0; k0 < K; k0 += 64) {
        __syncthreads();
#pragma unroll
        for (int jj = 0; jj < 2; jj++) {
            const int reg = jj * 4 + w;
            const int row = reg * 8 + srow;
            const int cs = sslot ^ (row & 7);
            glds16(&Y[(size_t)(m0 + row) * K + k0 + cs * 8], &As[reg * 512]);
            glds16(&Bt[(size_t)(n0 + row) * K + k0 + cs * 8], &Bs[reg * 512]);
        }
        __syncthreads();

#pragma unroll
        for (int kk = 0; kk < 2; kk++) {
            short8 af[2], bfr[2];
#pragma unroll
            for (int mt = 0; mt < 2; mt++) {
                const int row = wr * 32 + mt * 16 + l16;
                const int slot = ((kk << 2) | quad) ^ (row & 7);
                af[mt] = *(short8*)&As[row * 64 + slot * 8];
            }
#pragma unroll
            for (int nt = 0; nt < 2; nt++) {
                const int row = wc * 32 + nt * 16 + l16;
                const int slot = ((kk << 2) | quad) ^ (row & 7);
                bfr[nt] = *(short8*)&Bs[row * 64 + slot * 8];
            }
#pragma unroll
            for (int mt = 0; mt < 2; mt++)
#pragma unroll
                for (int nt = 0; nt < 2; nt++) acc[mt][nt] = MFMA16(af[mt], bfr[nt], acc[mt][nt]);
        }
    }

#pragma unroll
    for (int mt = 0; mt < 2; mt++)
#pragma unroll
        for (int nt = 0; nt < 2; nt++) {
            const int n = n0 + wc * 32 + nt * 16 + l16;
#pragma unroll
            for (int r = 0; r < 4; r++) {
                const int m = m0 + wr * 32 + mt * 16 + quad * 4 + r;
                out[(size_t)m * 1024 + n] = acc[mt][nt][r];
            }
        }
}

// ---------------------------------------------------------------------------
extern "C" void kernel_launch(void* const* d_in, const int* in_sizes, int n_in,
                              void* d_out, int out_size, void* d_ws, size_t ws_size,
                              hipStream_t stream) {
    const float* x  = (const float*)d_in[0];   // [2,2048,1024] f32
    const float* Wa = (const float*)d_in[1];   // [1024,3072]  f32
    const float* Wp = (const float*)d_in[2];   // [1024,1024]  f32
    float* out = (float*)d_out;                // [2,2048,1024] f32

    const size_t PB = (size_t)2048 * 1024;     // per-batch elements
    ushort* wtA = (ushort*)(out + PB);         // 6 MB W_attn^T bf16 (d_out b1
                                               //  half; dead after gemm1, and
                                               //  gemm2-b1 fully overwrites it)
    float2* tab = (float2*)(wtA + (size_t)3 * 1024 * 1024);
                                               // 512 KB trig table (d_out b1
                                               //  tail; dead after rope)

    if (ws_size >= (size_t)36 * 1024 * 1024) {
        // -------- merged-batch path: 8 launches ---------------------------
        ushort* qbA = (ushort*)d_ws;           // [2] x 4 MB  q  [b][H,T,HD]
        ushort* kbA = qbA + 2 * PB;            // [2] x 4 MB  k
        ushort* vtA = qbA + 4 * PB;            // [2] x 4 MB  v^T
        ushort* ybA = qbA + 6 * PB;            // [2] x 4 MB  x_bf16 / y
        ushort* wtP = qbA + 8 * PB;            // 2 MB  W_proj^T

        tp_k<<<dim3(96, 32), 256, 0, stream>>>(Wa, wtA, 1024, 3072);
        trig_k<<<dim3(256), 256, 0, stream>>>(tab);
        tp_k<<<dim3(32, 32), 256, 0, stream>>>(Wp, wtP, 1024, 1024);

        cvt_k<<<dim3(4096), 256, 0, stream>>>(x, ybA);
        gemm1_qkv_k<<<dim3(24, 16, 2), 256, 0, stream>>>(ybA, wtA, qbA, kbA, vtA);
        rope_k<<<dim3(16384), 256, 0, stream>>>(qbA, kbA, tab);
        attn_k<<<dim3(512), 256, 0, stream>>>(qbA, kbA, vtA, ybA);
        gemm2_proj_k<<<dim3(16, 32, 2), 256, 0, stream>>>(ybA, wtP, out);
        return;
    }

    // -------- fallback: per-batch loop (same kernels, z=1 grids) ----------
    ushort* qb  = (ushort*)d_ws;               // 4 MB bf16 q
    ushort* kb  = qb + PB;                     // 4 MB bf16 k
    ushort* vtb = kb + PB;                     // 4 MB bf16 v^T
    ushort* yb  = vtb + PB;                    // 4 MB bf16 y / x_bf16
    const bool hoistWp = ws_size >= (size_t)18 * 1024 * 1024;
    ushort* wtP_stable = yb + PB;              // d_ws + 16MB (only if hoistWp)

    tp_k<<<dim3(96, 32), 256, 0, stream>>>(Wa, wtA, 1024, 3072);
    trig_k<<<dim3(256), 256, 0, stream>>>(tab);
    if (hoistWp)
        tp_k<<<dim3(32, 32), 256, 0, stream>>>(Wp, wtP_stable, 1024, 1024);

    for (int b = 0; b < 2; b++) {
        cvt_k<<<dim3(2048), 256, 0, stream>>>(x + b * PB, yb);        // xb in yb slot
        gemm1_qkv_k<<<dim3(24, 16, 1), 256, 0, stream>>>(yb, wtA, qb, kb, vtb);
        rope_k<<<dim3(8192), 256, 0, stream>>>(qb, kb, tab);
        attn_k<<<dim3(256), 256, 0, stream>>>(qb, kb, vtb, yb);       // y over xb
        if (hoistWp) {
            gemm2_proj_k<<<dim3(16, 32, 1), 256, 0, stream>>>(yb, wtP_stable, out + b * PB);
        } else {
            tp_k<<<dim3(32, 32), 256, 0, stream>>>(Wp, qb, 1024, 1024);  // over dead q
            gemm2_proj_k<<<dim3(16, 32, 1), 256, 0, stream>>>(yb, qb, out + b * PB);
        }
    }
}

// Round 20
// 201.535 us; speedup vs baseline: 1.0202x; 1.0202x over previous
//
#include <hip/hip_runtime.h>

// ---------------------------------------------------------------------------
// qkv = x@W_attn; RoPE(q,k); flash-attn; y@W_proj
// B=2, T=2048, C=1024, H=16, HD=64.  I/O fp32; internal tensors bf16.
//
// R31 (R30 = REGRESSION, attn 58us @ 104 VGPR: fused dual-tile overloaded
// registers; dual-tile path closed after two failed variants):
//  * attn REVERTED to the measured R26/R27 single-tile form (48.6us):
//    grid 1024 merged (bid>>9) / 512 fallback.  Byte-identical body.
//  * gemm2 tile 64x64 -> 64x128 (the measured-good gemm1 transformation):
//    grid 8x32xZ = 512 blocks = 2/CU unchanged, 2x MFMA per staging byte,
//    half the Wp-panel fetch.  acc[2][4], ~75 VGPR, 24KB LDS.  Epilogue =
//    verified formula family (mt<2 @ wr*32, nt<4 @ wc*64).
//  * gemm1 128x128 (R27 measured), rope/cvt/tp/trig, merged launches
//    byte-identical to R27.
// ---------------------------------------------------------------------------

typedef __attribute__((ext_vector_type(8))) short short8;   // 8 bf16 = 4 VGPRs
typedef __attribute__((ext_vector_type(4))) float floatx4;  // MFMA C/D frag

__device__ __forceinline__ ushort f2bf(float f) {
    unsigned x = __float_as_uint(f);
    x += 0x7fffu + ((x >> 16) & 1u);   // round-to-nearest-even
    return (ushort)(x >> 16);
}
__device__ __forceinline__ float bf2f(ushort u) {
    return __uint_as_float(((unsigned)u) << 16);
}
__device__ __forceinline__ float exp2fast(float x) {   // 2^x, raw v_exp_f32
    float r;
    asm("v_exp_f32 %0, %1" : "=v"(r) : "v"(x));
    return r;
}
__device__ __forceinline__ unsigned cvtpk_bf16(float lo, float hi) {
    unsigned r;                                        // [bf16(hi)|bf16(lo)]
    asm("v_cvt_pk_bf16_f32 %0, %1, %2" : "=v"(r) : "v"(lo), "v"(hi));
    return r;
}

#define MFMA16(a, b, c) __builtin_amdgcn_mfma_f32_16x16x32_bf16((a), (b), (c), 0, 0, 0)

// async global->LDS, 16 bytes per lane.  LDS dest must be wave-uniform base;
// HW writes base + lane*16.  Global src is per-lane.
__device__ __forceinline__ void glds16(const ushort* g, ushort* l) {
    __builtin_amdgcn_global_load_lds(
        (const __attribute__((address_space(1))) unsigned int*)g,
        (__attribute__((address_space(3))) unsigned int*)l, 16, 0, 0);
}

// ---------------------------------------------------------------------------
// Transpose + cvt: src f32 [R][C] -> dst bf16 [C][R].  32x32 tiles via LDS.
// ---------------------------------------------------------------------------
__global__ __launch_bounds__(256) void tp_k(const float* __restrict__ src,
                                            ushort* __restrict__ dst,
                                            int R, int C) {
    __shared__ ushort t[32][34];
    const int c0 = blockIdx.x * 32, r0 = blockIdx.y * 32;
    const int tr = threadIdx.x >> 5, tc = threadIdx.x & 31;
#pragma unroll
    for (int j = 0; j < 4; j++)
        t[tr + j * 8][tc] = f2bf(src[(size_t)(r0 + tr + j * 8) * C + c0 + tc]);
    __syncthreads();
#pragma unroll
    for (int j = 0; j < 4; j++)
        dst[(size_t)(c0 + tr + j * 8) * R + r0 + tc] = t[tc][tr + j * 8];
}

// ---------------------------------------------------------------------------
// cvt: f32 -> bf16, 4 elems/thread.
// ---------------------------------------------------------------------------
__global__ __launch_bounds__(256) void cvt_k(const float* __restrict__ src,
                                             ushort* __restrict__ dst) {
    const size_t i = ((size_t)blockIdx.x * 256 + threadIdx.x) * 4;
    float4 t4 = *(const float4*)&src[i];
    *(ushort4*)&dst[i] = make_ushort4(f2bf(t4.x), f2bf(t4.y), f2bf(t4.z), f2bf(t4.w));
}

// ---------------------------------------------------------------------------
// trig table: tab[t][j] = (cos(t * 10000^(-j/32)), sin(...)), f64 math.
// ---------------------------------------------------------------------------
__global__ __launch_bounds__(256) void trig_k(float2* __restrict__ tab) {
    const int idx = blockIdx.x * 256 + threadIdx.x;   // [0, 65536)
    const int t = idx >> 5, j = idx & 31;
    const double inv = pow(10000.0, -(double)j / 32.0);
    const double ang = (double)t * inv;
    tab[idx] = make_float2((float)cos(ang), (float)sin(ang));
}

// ---------------------------------------------------------------------------
// GEMM1: qkv = xb[2048][1024](bf16) @ WaT^T (Bt bf16 [3072][1024])
// R27: 128x128 tile (grid 24x16xZ), BK=64, glds16, swizzled LDS.
// ---------------------------------------------------------------------------
__global__ __launch_bounds__(256, 3) void gemm1_qkv_k(const ushort* __restrict__ Ab,
                                                      const ushort* __restrict__ Bt,
                                                      ushort* __restrict__ qb,
                                                      ushort* __restrict__ kb,
                                                      ushort* __restrict__ vtb) {
    __shared__ __align__(16) ushort As[128 * 64];  // 16 KB, linear+swizzled
    __shared__ __align__(16) ushort Bs[128 * 64];  // 16 KB
    const size_t boff = (size_t)blockIdx.z * (2048u * 1024u);
    Ab += boff; qb += boff; kb += boff; vtb += boff;
    const int tid = threadIdx.x;
    const int m0 = blockIdx.y * 128, n0 = blockIdx.x * 128;
    const int w = tid >> 6, lane = tid & 63, quad = lane >> 4, l16 = lane & 15;
    const int wr = w >> 1, wc = w & 1;
    const int K = 1024;
    const int srow = lane >> 3, sslot = lane & 7;  // staging sub-row / slot

    floatx4 acc[4][4];
#pragma unroll
    for (int mt = 0; mt < 4; mt++)
#pragma unroll
        for (int nt = 0; nt < 4; nt++) acc[mt][nt] = (floatx4){0.f, 0.f, 0.f, 0.f};

    for (int k0 = 0; k0 < K; k0 += 64) {
        __syncthreads();   // all waves done reading prev tile
#pragma unroll
        for (int jj = 0; jj < 4; jj++) {
            const int reg = jj * 4 + w;
            const int row = reg * 8 + srow;
            const int cs = sslot ^ (row & 7);
            glds16(&Ab[(size_t)(m0 + row) * K + k0 + cs * 8], &As[reg * 512]);
        }
#pragma unroll
        for (int jj = 0; jj < 4; jj++) {
            const int reg = jj * 4 + w;
            const int row = reg * 8 + srow;
            const int cs = sslot ^ (row & 7);
            glds16(&Bt[(size_t)(n0 + row) * K + k0 + cs * 8], &Bs[reg * 512]);
        }
        __syncthreads();   // compiler drains vmcnt(0) before barrier

#pragma unroll
        for (int kk = 0; kk < 2; kk++) {
            short8 af[4], bfr[4];
#pragma unroll
            for (int mt = 0; mt < 4; mt++) {
                const int row = wr * 64 + mt * 16 + l16;
                const int slot = ((kk << 2) | quad) ^ (row & 7);
                af[mt] = *(short8*)&As[row * 64 + slot * 8];
            }
#pragma unroll
            for (int nt = 0; nt < 4; nt++) {
                const int row = wc * 64 + nt * 16 + l16;
                const int slot = ((kk << 2) | quad) ^ (row & 7);
                bfr[nt] = *(short8*)&Bs[row * 64 + slot * 8];
            }
#pragma unroll
            for (int mt = 0; mt < 4; mt++)
#pragma unroll
                for (int nt = 0; nt < 4; nt++) acc[mt][nt] = MFMA16(af[mt], bfr[nt], acc[mt][nt]);
        }
    }

    // Epilogue [R5-R14 verified 128x128 formulas]
#pragma unroll
    for (int nt = 0; nt < 4; nt++) {
        const int n = n0 + wc * 64 + nt * 16 + l16;
        const int seg = n >> 10;          // 0=q 1=k 2=v
        const int cn = n & 1023;
        const int h = cn >> 6, d = cn & 63;
#pragma unroll
        for (int mt = 0; mt < 4; mt++) {
#pragma unroll
            for (int r = 0; r < 4; r++) {
                const int t = m0 + wr * 64 + mt * 16 + quad * 4 + r;
                const ushort v = f2bf(acc[mt][nt][r]);
                if (seg == 0)      qb[((size_t)h * 2048 + t) * 64 + d] = v;
                else if (seg == 1) kb[((size_t)h * 2048 + t) * 64 + d] = v;
                else               vtb[((size_t)h * 64 + d) * 2048 + t] = v;
            }
        }
    }
}

// ---------------------------------------------------------------------------
// RoPE (roll variant), table-based trig.
// ---------------------------------------------------------------------------
__global__ __launch_bounds__(256) void rope_k(ushort* __restrict__ q,
                                              ushort* __restrict__ k,
                                              const float2* __restrict__ tab) {
    const int wid = blockIdx.x * 4 + (threadIdx.x >> 6);  // row
    const int lane = threadIdx.x & 63;
    const int t = wid & 2047;
    const float2 cs = tab[t * 32 + (lane & 31)];
    const float c = cs.x;
    const float s = cs.y;
    const size_t base = (size_t)wid * 64;

    float qv = bf2f(q[base + lane]);
    float qp = __shfl(qv, (lane + 63) & 63, 64);
    q[base + lane] = f2bf(qv * c + qp * s);

    float kv = bf2f(k[base + lane]);
    float kp = __shfl(kv, (lane + 63) & 63, 64);
    k[base + lane] = f2bf(kv * c + kp * s);
}

// ---------------------------------------------------------------------------
// Flash attention (causal), transposed form.  [R26/R27 measured form, 48.6us]
// R12: one q-tile per block.  R13: no Ps barrier.  R14: balanced qt remap.
// R21: KVBLK=128 + glds16 staging + exact-skip defer-max + setprio.
// R24: batch = bid>>9.  R26: mask-skip, exp2-domain softmax, cvt_pk P->bf16.
// ---------------------------------------------------------------------------
__global__ __launch_bounds__(256, 2) void attn_k(const ushort* __restrict__ q,
                                                 const ushort* __restrict__ k,
                                                 const ushort* __restrict__ vt,
                                                 ushort* __restrict__ y) {
    __shared__ __align__(16) ushort Ks[128 * 64];   // [key][d]  16 KB swz
    __shared__ __align__(16) ushort Vs[64 * 128];   // [d][key]  16 KB swz
    __shared__ __align__(16) ushort Ps[4][16][136]; // per-wave P^T [qrow][key]

    const int bid = blockIdx.x;
    const int b = bid >> 9;            // batch (0 under fallback grid 512)
    const int r9 = bid & 511;
    // r9 0..255: qt = 31,30,..,16 (16 heads each); 256..511: qt = 0,1,..,15
    const int qt = (r9 < 256) ? (31 - (r9 >> 4)) : ((r9 >> 4) - 16);
    const int h = r9 & 15;
    const size_t boff = (size_t)b * (2048u * 1024u);
    q += boff; k += boff; vt += boff; y += boff;
    const int tid = threadIdx.x, w = tid >> 6, lane = tid & 63;
    const int quad = lane >> 4, l16 = lane & 15;
    const int srow8 = lane >> 3, sslot8 = lane & 7;   // K staging (8 rows/KB)
    const int srow4 = lane >> 4, sslot16 = lane & 15; // V staging (4 rows/KB)

    const int q0 = qt * 64;
    const int qrow = q0 + w * 16 + l16;
    const int wrow0 = q0 + w * 16;     // min qrow in this wave
    const int nkt = (qt >> 1) + 1;     // 128-key tiles; trailing keys masked
    const float SC = 0.125f * 1.44269504f;  // score scale folded with log2(e)

    short8 qa0, qa1;
    {
        const ushort* qp = q + ((size_t)h * 2048 + qrow) * 64 + quad * 8;
        qa0 = *(const short8*)(qp);
        qa1 = *(const short8*)(qp + 32);
    }

    floatx4 O[4];
#pragma unroll
    for (int dt = 0; dt < 4; dt++) O[dt] = (floatx4){0.f, 0.f, 0.f, 0.f};
    float M = -30000.f, L = 0.f;

    for (int kt2 = 0; kt2 < nkt; kt2++) {
        const int kbase = kt2 * 128;
        __syncthreads();   // all waves done reading prev tile's LDS
        // K: 128 rows x 64 (128B rows, 8 chunks), 16 regions of 8 rows.
#pragma unroll
        for (int jj = 0; jj < 4; jj++) {
            const int reg = jj * 4 + w;
            const int row = reg * 8 + srow8;
            const int cs = sslot8 ^ (row & 7);
            glds16(&k[((size_t)h * 2048 + kbase + row) * 64 + cs * 8], &Ks[reg * 512]);
        }
        // V^T: 64 rows x 128 (256B rows, 16 chunks), 16 regions of 4 rows.
#pragma unroll
        for (int jj = 0; jj < 4; jj++) {
            const int reg = jj * 4 + w;
            const int row = reg * 4 + srow4;
            const int cs = sslot16 ^ (row & 15);
            glds16(&vt[((size_t)h * 64 + row) * 2048 + kbase + cs * 8], &Vs[reg * 512]);
        }
        __syncthreads();   // staging complete (vmcnt(0) drained at barrier)

        floatx4 s[8];
        __builtin_amdgcn_s_setprio(1);   // T5: QK^T MFMA cluster
#pragma unroll
        for (int nt = 0; nt < 8; nt++) {
            const int row = nt * 16 + l16;
            short8 ka0 = *(short8*)&Ks[row * 64 + ((quad ^ (row & 7)) * 8)];
            short8 ka1 = *(short8*)&Ks[row * 64 + (((4 | quad) ^ (row & 7)) * 8)];
            floatx4 z = (floatx4){0.f, 0.f, 0.f, 0.f};
            z = MFMA16(ka0, qa0, z);
            z = MFMA16(ka1, qa1, z);
            s[nt] = z;
        }
        __builtin_amdgcn_s_setprio(0);

        // scale (+ causal mask only when this wave's rows can be masked)
        if (kbase + 127 <= wrow0) {
#pragma unroll
            for (int nt = 0; nt < 8; nt++)
#pragma unroll
                for (int r = 0; r < 4; r++) s[nt][r] *= SC;
        } else {
#pragma unroll
            for (int nt = 0; nt < 8; nt++)
#pragma unroll
                for (int r = 0; r < 4; r++) {
                    const int kidx = kbase + nt * 16 + quad * 4 + r;
                    const float vv = s[nt][r] * SC;
                    s[nt][r] = (kidx > qrow) ? -30000.f : vv;
                }
        }

        // tree max over 32 values (max is exactly associative)
        float mr[8];
#pragma unroll
        for (int nt = 0; nt < 8; nt++)
            mr[nt] = fmaxf(fmaxf(s[nt][0], s[nt][1]), fmaxf(s[nt][2], s[nt][3]));
        float mx = fmaxf(fmaxf(fmaxf(mr[0], mr[1]), fmaxf(mr[2], mr[3])),
                         fmaxf(fmaxf(mr[4], mr[5]), fmaxf(mr[6], mr[7])));
        mx = fmaxf(mx, __shfl_xor(mx, 16, 64));
        mx = fmaxf(mx, __shfl_xor(mx, 32, 64));

        // exact-skip defer-max: if no lane's max grew, Mn==M and alpha==1
        // exactly -> skipping rescale is bit-identical.
        if (!__all(mx <= M)) {
            const float Mn = fmaxf(M, mx);
            const float alpha = exp2fast(M - Mn);
            L *= alpha;
#pragma unroll
            for (int dt = 0; dt < 4; dt++) O[dt] *= alpha;
            M = Mn;
        }

        float sum = 0.f;
#pragma unroll
        for (int nt = 0; nt < 8; nt++)
#pragma unroll
            for (int r = 0; r < 4; r++) {
                const float pv = exp2fast(s[nt][r] - M);
                s[nt][r] = pv;
                sum += pv;
            }
        sum += __shfl_xor(sum, 16, 64);
        sum += __shfl_xor(sum, 32, 64);
        L += sum;

#pragma unroll
        for (int nt = 0; nt < 8; nt++) {
            uint2 pk2;
            pk2.x = cvtpk_bf16(s[nt][0], s[nt][1]);
            pk2.y = cvtpk_bf16(s[nt][2], s[nt][3]);
            *(uint2*)&Ps[w][l16][nt * 16 + quad * 4] = pk2;
        }
        // no barrier: Ps[w] is written and read only by wave w; in-wave DS
        // ordering is enforced by the compiler's lgkmcnt tracking.

        short8 pb[4];
#pragma unroll
        for (int ks = 0; ks < 4; ks++)
            pb[ks] = *(short8*)&Ps[w][l16][ks * 32 + quad * 8];
        __builtin_amdgcn_s_setprio(1);   // T5: PV MFMA cluster
#pragma unroll
        for (int dt = 0; dt < 4; dt++) {
            const int row = dt * 16 + l16;
#pragma unroll
            for (int ks = 0; ks < 4; ks++) {
                const int cc = (ks * 4 + quad) ^ (row & 15);
                short8 va = *(short8*)&Vs[row * 128 + cc * 8];
                O[dt] = MFMA16(va, pb[ks], O[dt]);
            }
        }
        __builtin_amdgcn_s_setprio(0);
    }

    const float rl = 1.0f / L;
#pragma unroll
    for (int dt = 0; dt < 4; dt++) {
        ushort4 o4 = make_ushort4(f2bf(O[dt][0] * rl), f2bf(O[dt][1] * rl),
                                  f2bf(O[dt][2] * rl), f2bf(O[dt][3] * rl));
        *(ushort4*)&y[(size_t)qrow * 1024 + h * 64 + dt * 16 + quad * 4] = o4;
    }
}

// ---------------------------------------------------------------------------
// GEMM2: out(f32) = y[2048][1024](bf16) @ WpT^T (bf16 [1024][1024])
// R31: 64(m)x128(n) tile (grid 8x32xZ = 512 blocks = 2/CU), BK=64, glds16,
// swizzled LDS — 2x MFMA per staging byte vs the 64x64 form.
// ---------------------------------------------------------------------------
__global__ __launch_bounds__(256, 2) void gemm2_proj_k(const ushort* __restrict__ Y,
                                                       const ushort* __restrict__ Bt,
                                                       float* __restrict__ out) {
    __shared__ __align__(16) ushort As[64 * 64];   // 8 KB, linear+swizzled
    __shared__ __align__(16) ushort Bs[128 * 64];  // 16 KB
    const size_t boff = (size_t)blockIdx.z * (2048u * 1024u);
    Y += boff; out += boff;
    const int tid = threadIdx.x;
    const int m0 = blockIdx.y * 64, n0 = blockIdx.x * 128;
    const int w = tid >> 6, lane = tid & 63, quad = lane >> 4, l16 = lane & 15;
    const int wr = w >> 1, wc = w & 1;
    const int K = 1024;
    const int srow = lane >> 3, sslot = lane & 7;

    floatx4 acc[2][4];
#pragma unroll
    for (int mt = 0; mt < 2; mt++)
#pragma unroll
        for (int nt = 0; nt < 4; nt++) acc[mt][nt] = (floatx4){0.f, 0.f, 0.f, 0.f};

    for (int k0 = 0; k0 < K; k0 += 64) {
        __syncthreads();
        // A: 64 rows = 8 regions (jj<2); B: 128 rows = 16 regions (jj<4)
#pragma unroll
        for (int jj = 0; jj < 2; jj++) {
            const int reg = jj * 4 + w;
            const int row = reg * 8 + srow;
            const int cs = sslot ^ (row & 7);
            glds16(&Y[(size_t)(m0 + row) * K + k0 + cs * 8], &As[reg * 512]);
        }
#pragma unroll
        for (int jj = 0; jj < 4; jj++) {
            const int reg = jj * 4 + w;
            const int row = reg * 8 + srow;
            const int cs = sslot ^ (row & 7);
            glds16(&Bt[(size_t)(n0 + row) * K + k0 + cs * 8], &Bs[reg * 512]);
        }
        __syncthreads();

#pragma unroll
        for (int kk = 0; kk < 2; kk++) {
            short8 af[2], bfr[4];
#pragma unroll
            for (int mt = 0; mt < 2; mt++) {
                const int row = wr * 32 + mt * 16 + l16;
                const int slot = ((kk << 2) | quad) ^ (row & 7);
                af[mt] = *(short8*)&As[row * 64 + slot * 8];
            }
#pragma unroll
            for (int nt = 0; nt < 4; nt++) {
                const int row = wc * 64 + nt * 16 + l16;
                const int slot = ((kk << 2) | quad) ^ (row & 7);
                bfr[nt] = *(short8*)&Bs[row * 64 + slot * 8];
            }
#pragma unroll
            for (int mt = 0; mt < 2; mt++)
#pragma unroll
                for (int nt = 0; nt < 4; nt++) acc[mt][nt] = MFMA16(af[mt], bfr[nt], acc[mt][nt]);
        }
    }

#pragma unroll
    for (int mt = 0; mt < 2; mt++)
#pragma unroll
        for (int nt = 0; nt < 4; nt++) {
            const int n = n0 + wc * 64 + nt * 16 + l16;
#pragma unroll
            for (int r = 0; r < 4; r++) {
                const int m = m0 + wr * 32 + mt * 16 + quad * 4 + r;
                out[(size_t)m * 1024 + n] = acc[mt][nt][r];
            }
        }
}

// ---------------------------------------------------------------------------
extern "C" void kernel_launch(void* const* d_in, const int* in_sizes, int n_in,
                              void* d_out, int out_size, void* d_ws, size_t ws_size,
                              hipStream_t stream) {
    const float* x  = (const float*)d_in[0];   // [2,2048,1024] f32
    const float* Wa = (const float*)d_in[1];   // [1024,3072]  f32
    const float* Wp = (const float*)d_in[2];   // [1024,1024]  f32
    float* out = (float*)d_out;                // [2,2048,1024] f32

    const size_t PB = (size_t)2048 * 1024;     // per-batch elements
    ushort* wtA = (ushort*)(out + PB);         // 6 MB W_attn^T bf16 (d_out b1
                                               //  half; dead after gemm1, and
                                               //  gemm2-b1 fully overwrites it)
    float2* tab = (float2*)(wtA + (size_t)3 * 1024 * 1024);
                                               // 512 KB trig table (d_out b1
                                               //  tail; dead after rope)

    if (ws_size >= (size_t)36 * 1024 * 1024) {
        // -------- merged-batch path: 8 launches ---------------------------
        ushort* qbA = (ushort*)d_ws;           // [2] x 4 MB  q  [b][H,T,HD]
        ushort* kbA = qbA + 2 * PB;            // [2] x 4 MB  k
        ushort* vtA = qbA + 4 * PB;            // [2] x 4 MB  v^T
        ushort* ybA = qbA + 6 * PB;            // [2] x 4 MB  x_bf16 / y
        ushort* wtP = qbA + 8 * PB;            // 2 MB  W_proj^T

        tp_k<<<dim3(96, 32), 256, 0, stream>>>(Wa, wtA, 1024, 3072);
        trig_k<<<dim3(256), 256, 0, stream>>>(tab);
        tp_k<<<dim3(32, 32), 256, 0, stream>>>(Wp, wtP, 1024, 1024);

        cvt_k<<<dim3(4096), 256, 0, stream>>>(x, ybA);
        gemm1_qkv_k<<<dim3(24, 16, 2), 256, 0, stream>>>(ybA, wtA, qbA, kbA, vtA);
        rope_k<<<dim3(16384), 256, 0, stream>>>(qbA, kbA, tab);
        attn_k<<<dim3(1024), 256, 0, stream>>>(qbA, kbA, vtA, ybA);
        gemm2_proj_k<<<dim3(8, 32, 2), 256, 0, stream>>>(ybA, wtP, out);
        return;
    }

    // -------- fallback: per-batch loop (same kernels, z=1 grids) ----------
    ushort* qb  = (ushort*)d_ws;               // 4 MB bf16 q
    ushort* kb  = qb + PB;                     // 4 MB bf16 k
    ushort* vtb = kb + PB;                     // 4 MB bf16 v^T
    ushort* yb  = vtb + PB;                    // 4 MB bf16 y / x_bf16
    const bool hoistWp = ws_size >= (size_t)18 * 1024 * 1024;
    ushort* wtP_stable = yb + PB;              // d_ws + 16MB (only if hoistWp)

    tp_k<<<dim3(96, 32), 256, 0, stream>>>(Wa, wtA, 1024, 3072);
    trig_k<<<dim3(256), 256, 0, stream>>>(tab);
    if (hoistWp)
        tp_k<<<dim3(32, 32), 256, 0, stream>>>(Wp, wtP_stable, 1024, 1024);

    for (int b = 0; b < 2; b++) {
        cvt_k<<<dim3(2048), 256, 0, stream>>>(x + b * PB, yb);        // xb in yb slot
        gemm1_qkv_k<<<dim3(24, 16, 1), 256, 0, stream>>>(yb, wtA, qb, kb, vtb);
        rope_k<<<dim3(8192), 256, 0, stream>>>(qb, kb, tab);
        attn_k<<<dim3(512), 256, 0, stream>>>(qb, kb, vtb, yb);       // y over xb
        if (hoistWp) {
            gemm2_proj_k<<<dim3(8, 32, 1), 256, 0, stream>>>(yb, wtP_stable, out + b * PB);
        } else {
            tp_k<<<dim3(32, 32), 256, 0, stream>>>(Wp, qb, 1024, 1024);  // over dead q
            gemm2_proj_k<<<dim3(8, 32, 1), 256, 0, stream>>>(yb, qb, out + b * PB);
        }
    }
}

// Round 21
// 199.650 us; speedup vs baseline: 1.0298x; 1.0094x over previous
//
#include <hip/hip_runtime.h>

// ---------------------------------------------------------------------------
// qkv = x@W_attn; RoPE(q,k); flash-attn; y@W_proj
// B=2, T=2048, C=1024, H=16, HD=64.  I/O fp32; internal tensors bf16.
//
// R32 (R31 measured 201.54us, attn restored to 48.6us; plateau ~200us; last
// untested attn quadrant = small-LDS x high-occupancy):
//  * attn KVBLK 128 -> 64 with __launch_bounds__(256,4): LDS 25.2KB/block
//    (x4 = 101 <= 160), VGPR ~52 << 128-cap -> 4 blocks/CU genuinely
//    attainable (R25's 3-block failure was at 49KB).  Grid 1024 = exact
//    capacity; quarter-wise LPT map gives EVERY CU exactly 66 key-tile
//    units (constant).  Body = measured R18 KVBLK=64 kernel + measured R26
//    softmax upgrades (mask-skip / exp2-domain / cvt_pk) — mechanical
//    recombination of verified pieces.  A/B: 4-way chain overlap vs 2x
//    serial sections.
//  * gemm1 128x128, gemm2 64x128, rope/cvt/tp/trig, merged launches
//    byte-identical to R31.
// ---------------------------------------------------------------------------

typedef __attribute__((ext_vector_type(8))) short short8;   // 8 bf16 = 4 VGPRs
typedef __attribute__((ext_vector_type(4))) float floatx4;  // MFMA C/D frag

__device__ __forceinline__ ushort f2bf(float f) {
    unsigned x = __float_as_uint(f);
    x += 0x7fffu + ((x >> 16) & 1u);   // round-to-nearest-even
    return (ushort)(x >> 16);
}
__device__ __forceinline__ float bf2f(ushort u) {
    return __uint_as_float(((unsigned)u) << 16);
}
__device__ __forceinline__ float exp2fast(float x) {   // 2^x, raw v_exp_f32
    float r;
    asm("v_exp_f32 %0, %1" : "=v"(r) : "v"(x));
    return r;
}
__device__ __forceinline__ unsigned cvtpk_bf16(float lo, float hi) {
    unsigned r;                                        // [bf16(hi)|bf16(lo)]
    asm("v_cvt_pk_bf16_f32 %0, %1, %2" : "=v"(r) : "v"(lo), "v"(hi));
    return r;
}

#define MFMA16(a, b, c) __builtin_amdgcn_mfma_f32_16x16x32_bf16((a), (b), (c), 0, 0, 0)

// async global->LDS, 16 bytes per lane.  LDS dest must be wave-uniform base;
// HW writes base + lane*16.  Global src is per-lane.
__device__ __forceinline__ void glds16(const ushort* g, ushort* l) {
    __builtin_amdgcn_global_load_lds(
        (const __attribute__((address_space(1))) unsigned int*)g,
        (__attribute__((address_space(3))) unsigned int*)l, 16, 0, 0);
}

// ---------------------------------------------------------------------------
// Transpose + cvt: src f32 [R][C] -> dst bf16 [C][R].  32x32 tiles via LDS.
// ---------------------------------------------------------------------------
__global__ __launch_bounds__(256) void tp_k(const float* __restrict__ src,
                                            ushort* __restrict__ dst,
                                            int R, int C) {
    __shared__ ushort t[32][34];
    const int c0 = blockIdx.x * 32, r0 = blockIdx.y * 32;
    const int tr = threadIdx.x >> 5, tc = threadIdx.x & 31;
#pragma unroll
    for (int j = 0; j < 4; j++)
        t[tr + j * 8][tc] = f2bf(src[(size_t)(r0 + tr + j * 8) * C + c0 + tc]);
    __syncthreads();
#pragma unroll
    for (int j = 0; j < 4; j++)
        dst[(size_t)(c0 + tr + j * 8) * R + r0 + tc] = t[tc][tr + j * 8];
}

// ---------------------------------------------------------------------------
// cvt: f32 -> bf16, 4 elems/thread.
// ---------------------------------------------------------------------------
__global__ __launch_bounds__(256) void cvt_k(const float* __restrict__ src,
                                             ushort* __restrict__ dst) {
    const size_t i = ((size_t)blockIdx.x * 256 + threadIdx.x) * 4;
    float4 t4 = *(const float4*)&src[i];
    *(ushort4*)&dst[i] = make_ushort4(f2bf(t4.x), f2bf(t4.y), f2bf(t4.z), f2bf(t4.w));
}

// ---------------------------------------------------------------------------
// trig table: tab[t][j] = (cos(t * 10000^(-j/32)), sin(...)), f64 math.
// ---------------------------------------------------------------------------
__global__ __launch_bounds__(256) void trig_k(float2* __restrict__ tab) {
    const int idx = blockIdx.x * 256 + threadIdx.x;   // [0, 65536)
    const int t = idx >> 5, j = idx & 31;
    const double inv = pow(10000.0, -(double)j / 32.0);
    const double ang = (double)t * inv;
    tab[idx] = make_float2((float)cos(ang), (float)sin(ang));
}

// ---------------------------------------------------------------------------
// GEMM1: qkv = xb[2048][1024](bf16) @ WaT^T (Bt bf16 [3072][1024])
// R27: 128x128 tile (grid 24x16xZ), BK=64, glds16, swizzled LDS.
// ---------------------------------------------------------------------------
__global__ __launch_bounds__(256, 3) void gemm1_qkv_k(const ushort* __restrict__ Ab,
                                                      const ushort* __restrict__ Bt,
                                                      ushort* __restrict__ qb,
                                                      ushort* __restrict__ kb,
                                                      ushort* __restrict__ vtb) {
    __shared__ __align__(16) ushort As[128 * 64];  // 16 KB, linear+swizzled
    __shared__ __align__(16) ushort Bs[128 * 64];  // 16 KB
    const size_t boff = (size_t)blockIdx.z * (2048u * 1024u);
    Ab += boff; qb += boff; kb += boff; vtb += boff;
    const int tid = threadIdx.x;
    const int m0 = blockIdx.y * 128, n0 = blockIdx.x * 128;
    const int w = tid >> 6, lane = tid & 63, quad = lane >> 4, l16 = lane & 15;
    const int wr = w >> 1, wc = w & 1;
    const int K = 1024;
    const int srow = lane >> 3, sslot = lane & 7;  // staging sub-row / slot

    floatx4 acc[4][4];
#pragma unroll
    for (int mt = 0; mt < 4; mt++)
#pragma unroll
        for (int nt = 0; nt < 4; nt++) acc[mt][nt] = (floatx4){0.f, 0.f, 0.f, 0.f};

    for (int k0 = 0; k0 < K; k0 += 64) {
        __syncthreads();   // all waves done reading prev tile
#pragma unroll
        for (int jj = 0; jj < 4; jj++) {
            const int reg = jj * 4 + w;
            const int row = reg * 8 + srow;
            const int cs = sslot ^ (row & 7);
            glds16(&Ab[(size_t)(m0 + row) * K + k0 + cs * 8], &As[reg * 512]);
        }
#pragma unroll
        for (int jj = 0; jj < 4; jj++) {
            const int reg = jj * 4 + w;
            const int row = reg * 8 + srow;
            const int cs = sslot ^ (row & 7);
            glds16(&Bt[(size_t)(n0 + row) * K + k0 + cs * 8], &Bs[reg * 512]);
        }
        __syncthreads();   // compiler drains vmcnt(0) before barrier

#pragma unroll
        for (int kk = 0; kk < 2; kk++) {
            short8 af[4], bfr[4];
#pragma unroll
            for (int mt = 0; mt < 4; mt++) {
                const int row = wr * 64 + mt * 16 + l16;
                const int slot = ((kk << 2) | quad) ^ (row & 7);
                af[mt] = *(short8*)&As[row * 64 + slot * 8];
            }
#pragma unroll
            for (int nt = 0; nt < 4; nt++) {
                const int row = wc * 64 + nt * 16 + l16;
                const int slot = ((kk << 2) | quad) ^ (row & 7);
                bfr[nt] = *(short8*)&Bs[row * 64 + slot * 8];
            }
#pragma unroll
            for (int mt = 0; mt < 4; mt++)
#pragma unroll
                for (int nt = 0; nt < 4; nt++) acc[mt][nt] = MFMA16(af[mt], bfr[nt], acc[mt][nt]);
        }
    }

    // Epilogue [R5-R14 verified 128x128 formulas]
#pragma unroll
    for (int nt = 0; nt < 4; nt++) {
        const int n = n0 + wc * 64 + nt * 16 + l16;
        const int seg = n >> 10;          // 0=q 1=k 2=v
        const int cn = n & 1023;
        const int h = cn >> 6, d = cn & 63;
#pragma unroll
        for (int mt = 0; mt < 4; mt++) {
#pragma unroll
            for (int r = 0; r < 4; r++) {
                const int t = m0 + wr * 64 + mt * 16 + quad * 4 + r;
                const ushort v = f2bf(acc[mt][nt][r]);
                if (seg == 0)      qb[((size_t)h * 2048 + t) * 64 + d] = v;
                else if (seg == 1) kb[((size_t)h * 2048 + t) * 64 + d] = v;
                else               vtb[((size_t)h * 64 + d) * 2048 + t] = v;
            }
        }
    }
}

// ---------------------------------------------------------------------------
// RoPE (roll variant), table-based trig.
// ---------------------------------------------------------------------------
__global__ __launch_bounds__(256) void rope_k(ushort* __restrict__ q,
                                              ushort* __restrict__ k,
                                              const float2* __restrict__ tab) {
    const int wid = blockIdx.x * 4 + (threadIdx.x >> 6);  // row
    const int lane = threadIdx.x & 63;
    const int t = wid & 2047;
    const float2 cs = tab[t * 32 + (lane & 31)];
    const float c = cs.x;
    const float s = cs.y;
    const size_t base = (size_t)wid * 64;

    float qv = bf2f(q[base + lane]);
    float qp = __shfl(qv, (lane + 63) & 63, 64);
    q[base + lane] = f2bf(qv * c + qp * s);

    float kv = bf2f(k[base + lane]);
    float kp = __shfl(kv, (lane + 63) & 63, 64);
    k[base + lane] = f2bf(kv * c + kp * s);
}

// ---------------------------------------------------------------------------
// Flash attention (causal), transposed form.
// R13: no Ps barrier.  R18: KVBLK=64 glds16 staging, both-sides XOR.
// R26: mask-skip, exp2-domain softmax, cvt_pk P->bf16.  R21: exact-skip.
// R32: __launch_bounds__(256,4) — 25.2KB LDS -> 4 blocks/CU; grid 1024 =
//      exact capacity; quarter-LPT gives every CU 66 key-tile units.
//      b = bid>>9 (quarters 0,1 = batch0; 2,3 = batch1).
// ---------------------------------------------------------------------------
__global__ __launch_bounds__(256, 4) void attn_k(const ushort* __restrict__ q,
                                                 const ushort* __restrict__ k,
                                                 const ushort* __restrict__ vt,
                                                 ushort* __restrict__ y) {
    __shared__ __align__(16) ushort Ks[64 * 64];    // [key][d]  8 KB swz
    __shared__ __align__(16) ushort Vs[64 * 64];    // [d][key]  8 KB swz
    __shared__ __align__(16) ushort Ps[4][16][72];  // per-wave P^T [qrow][key]

    const int bid = blockIdx.x;
    const int b = bid >> 9;            // batch (0 under fallback grid 512)
    const int r9 = bid & 511;
    // r9 0..255: qt = 31,30,..,16 (16 heads each); 256..511: qt = 0,1,..,15
    const int qt = (r9 < 256) ? (31 - (r9 >> 4)) : ((r9 >> 4) - 16);
    const int h = r9 & 15;
    const size_t boff = (size_t)b * (2048u * 1024u);
    q += boff; k += boff; vt += boff; y += boff;
    const int tid = threadIdx.x, w = tid >> 6, lane = tid & 63;
    const int quad = lane >> 4, l16 = lane & 15;
    const int srow8 = lane >> 3, sslot8 = lane & 7;   // staging (8 rows/KB)

    const int q0 = qt * 64;
    const int qrow = q0 + w * 16 + l16;
    const int wrow0 = q0 + w * 16;     // min qrow in this wave
    const int nkt = qt + 1;            // 64-key tiles
    const float SC = 0.125f * 1.44269504f;  // score scale folded with log2(e)

    short8 qa0, qa1;
    {
        const ushort* qp = q + ((size_t)h * 2048 + qrow) * 64 + quad * 8;
        qa0 = *(const short8*)(qp);
        qa1 = *(const short8*)(qp + 32);
    }

    floatx4 O[4];
#pragma unroll
    for (int dt = 0; dt < 4; dt++) O[dt] = (floatx4){0.f, 0.f, 0.f, 0.f};
    float M = -30000.f, L = 0.f;

    for (int kt = 0; kt < nkt; kt++) {
        const int kbase = kt * 64;
        __syncthreads();   // all waves done reading prev tile's LDS
        // K[64][64] and V^T[64][64]: 8 regions each of 8 rows; both-sides XOR.
#pragma unroll
        for (int jj = 0; jj < 2; jj++) {
            const int reg = jj * 4 + w;
            const int row = reg * 8 + srow8;
            const int cs = sslot8 ^ (row & 7);
            glds16(&k[((size_t)h * 2048 + kbase + row) * 64 + cs * 8], &Ks[reg * 512]);
            glds16(&vt[((size_t)h * 64 + row) * 2048 + kbase + cs * 8], &Vs[reg * 512]);
        }
        __syncthreads();   // staging complete (vmcnt(0) drained at barrier)

        floatx4 s[4];
        __builtin_amdgcn_s_setprio(1);   // T5: QK^T MFMA cluster
#pragma unroll
        for (int nt = 0; nt < 4; nt++) {
            const int row = nt * 16 + l16;
            short8 ka0 = *(short8*)&Ks[row * 64 + ((quad ^ (row & 7)) * 8)];
            short8 ka1 = *(short8*)&Ks[row * 64 + (((4 | quad) ^ (row & 7)) * 8)];
            floatx4 z = (floatx4){0.f, 0.f, 0.f, 0.f};
            z = MFMA16(ka0, qa0, z);
            z = MFMA16(ka1, qa1, z);
            s[nt] = z;
        }
        __builtin_amdgcn_s_setprio(0);

        // scale (+ causal mask only when this wave's rows can be masked)
        if (kbase + 63 <= wrow0) {
#pragma unroll
            for (int nt = 0; nt < 4; nt++)
#pragma unroll
                for (int r = 0; r < 4; r++) s[nt][r] *= SC;
        } else {
#pragma unroll
            for (int nt = 0; nt < 4; nt++)
#pragma unroll
                for (int r = 0; r < 4; r++) {
                    const int kidx = kbase + nt * 16 + quad * 4 + r;
                    const float vv = s[nt][r] * SC;
                    s[nt][r] = (kidx > qrow) ? -30000.f : vv;
                }
        }

        // tree max over 16 values (max is exactly associative)
        float mr[4];
#pragma unroll
        for (int nt = 0; nt < 4; nt++)
            mr[nt] = fmaxf(fmaxf(s[nt][0], s[nt][1]), fmaxf(s[nt][2], s[nt][3]));
        float mx = fmaxf(fmaxf(mr[0], mr[1]), fmaxf(mr[2], mr[3]));
        mx = fmaxf(mx, __shfl_xor(mx, 16, 64));
        mx = fmaxf(mx, __shfl_xor(mx, 32, 64));

        // exact-skip defer-max: if no lane's max grew, Mn==M and alpha==1
        // exactly -> skipping rescale is bit-identical.
        if (!__all(mx <= M)) {
            const float Mn = fmaxf(M, mx);
            const float alpha = exp2fast(M - Mn);
            L *= alpha;
#pragma unroll
            for (int dt = 0; dt < 4; dt++) O[dt] *= alpha;
            M = Mn;
        }

        float sum = 0.f;
#pragma unroll
        for (int nt = 0; nt < 4; nt++)
#pragma unroll
            for (int r = 0; r < 4; r++) {
                const float pv = exp2fast(s[nt][r] - M);
                s[nt][r] = pv;
                sum += pv;
            }
        sum += __shfl_xor(sum, 16, 64);
        sum += __shfl_xor(sum, 32, 64);
        L += sum;

#pragma unroll
        for (int nt = 0; nt < 4; nt++) {
            uint2 pk2;
            pk2.x = cvtpk_bf16(s[nt][0], s[nt][1]);
            pk2.y = cvtpk_bf16(s[nt][2], s[nt][3]);
            *(uint2*)&Ps[w][l16][nt * 16 + quad * 4] = pk2;
        }
        // no barrier: Ps[w] is written and read only by wave w; in-wave DS
        // ordering is enforced by the compiler's lgkmcnt tracking.

        short8 pb0 = *(short8*)&Ps[w][l16][quad * 8];
        short8 pb1 = *(short8*)&Ps[w][l16][32 + quad * 8];
        __builtin_amdgcn_s_setprio(1);   // T5: PV MFMA cluster
#pragma unroll
        for (int dt = 0; dt < 4; dt++) {
            const int row = dt * 16 + l16;
            short8 va0 = *(short8*)&Vs[row * 64 + ((quad ^ (row & 7)) * 8)];
            short8 va1 = *(short8*)&Vs[row * 64 + (((4 | quad) ^ (row & 7)) * 8)];
            O[dt] = MFMA16(va0, pb0, O[dt]);
            O[dt] = MFMA16(va1, pb1, O[dt]);
        }
        __builtin_amdgcn_s_setprio(0);
    }

    const float rl = 1.0f / L;
#pragma unroll
    for (int dt = 0; dt < 4; dt++) {
        ushort4 o4 = make_ushort4(f2bf(O[dt][0] * rl), f2bf(O[dt][1] * rl),
                                  f2bf(O[dt][2] * rl), f2bf(O[dt][3] * rl));
        *(ushort4*)&y[(size_t)qrow * 1024 + h * 64 + dt * 16 + quad * 4] = o4;
    }
}

// ---------------------------------------------------------------------------
// GEMM2: out(f32) = y[2048][1024](bf16) @ WpT^T (bf16 [1024][1024])
// R31: 64(m)x128(n) tile (grid 8x32xZ), BK=64, glds16, swizzled LDS.
// ---------------------------------------------------------------------------
__global__ __launch_bounds__(256, 2) void gemm2_proj_k(const ushort* __restrict__ Y,
                                                       const ushort* __restrict__ Bt,
                                                       float* __restrict__ out) {
    __shared__ __align__(16) ushort As[64 * 64];   // 8 KB, linear+swizzled
    __shared__ __align__(16) ushort Bs[128 * 64];  // 16 KB
    const size_t boff = (size_t)blockIdx.z * (2048u * 1024u);
    Y += boff; out += boff;
    const int tid = threadIdx.x;
    const int m0 = blockIdx.y * 64, n0 = blockIdx.x * 128;
    const int w = tid >> 6, lane = tid & 63, quad = lane >> 4, l16 = lane & 15;
    const int wr = w >> 1, wc = w & 1;
    const int K = 1024;
    const int srow = lane >> 3, sslot = lane & 7;

    floatx4 acc[2][4];
#pragma unroll
    for (int mt = 0; mt < 2; mt++)
#pragma unroll
        for (int nt = 0; nt < 4; nt++) acc[mt][nt] = (floatx4){0.f, 0.f, 0.f, 0.f};

    for (int k0 = 0; k0 < K; k0 += 64) {
        __syncthreads();
        // A: 64 rows = 8 regions (jj<2); B: 128 rows = 16 regions (jj<4)
#pragma unroll
        for (int jj = 0; jj < 2; jj++) {
            const int reg = jj * 4 + w;
            const int row = reg * 8 + srow;
            const int cs = sslot ^ (row & 7);
            glds16(&Y[(size_t)(m0 + row) * K + k0 + cs * 8], &As[reg * 512]);
        }
#pragma unroll
        for (int jj = 0; jj < 4; jj++) {
            const int reg = jj * 4 + w;
            const int row = reg * 8 + srow;
            const int cs = sslot ^ (row & 7);
            glds16(&Bt[(size_t)(n0 + row) * K + k0 + cs * 8], &Bs[reg * 512]);
        }
        __syncthreads();

#pragma unroll
        for (int kk = 0; kk < 2; kk++) {
            short8 af[2], bfr[4];
#pragma unroll
            for (int mt = 0; mt < 2; mt++) {
                const int row = wr * 32 + mt * 16 + l16;
                const int slot = ((kk << 2) | quad) ^ (row & 7);
                af[mt] = *(short8*)&As[row * 64 + slot * 8];
            }
#pragma unroll
            for (int nt = 0; nt < 4; nt++) {
                const int row = wc * 64 + nt * 16 + l16;
                const int slot = ((kk << 2) | quad) ^ (row & 7);
                bfr[nt] = *(short8*)&Bs[row * 64 + slot * 8];
            }
#pragma unroll
            for (int mt = 0; mt < 2; mt++)
#pragma unroll
                for (int nt = 0; nt < 4; nt++) acc[mt][nt] = MFMA16(af[mt], bfr[nt], acc[mt][nt]);
        }
    }

#pragma unroll
    for (int mt = 0; mt < 2; mt++)
#pragma unroll
        for (int nt = 0; nt < 4; nt++) {
            const int n = n0 + wc * 64 + nt * 16 + l16;
#pragma unroll
            for (int r = 0; r < 4; r++) {
                const int m = m0 + wr * 32 + mt * 16 + quad * 4 + r;
                out[(size_t)m * 1024 + n] = acc[mt][nt][r];
            }
        }
}

// ---------------------------------------------------------------------------
extern "C" void kernel_launch(void* const* d_in, const int* in_sizes, int n_in,
                              void* d_out, int out_size, void* d_ws, size_t ws_size,
                              hipStream_t stream) {
    const float* x  = (const float*)d_in[0];   // [2,2048,1024] f32
    const float* Wa = (const float*)d_in[1];   // [1024,3072]  f32
    const float* Wp = (const float*)d_in[2];   // [1024,1024]  f32
    float* out = (float*)d_out;                // [2,2048,1024] f32

    const size_t PB = (size_t)2048 * 1024;     // per-batch elements
    ushort* wtA = (ushort*)(out + PB);         // 6 MB W_attn^T bf16 (d_out b1
                                               //  half; dead after gemm1, and
                                               //  gemm2-b1 fully overwrites it)
    float2* tab = (float2*)(wtA + (size_t)3 * 1024 * 1024);
                                               // 512 KB trig table (d_out b1
                                               //  tail; dead after rope)

    if (ws_size >= (size_t)36 * 1024 * 1024) {
        // -------- merged-batch path: 8 launches ---------------------------
        ushort* qbA = (ushort*)d_ws;           // [2] x 4 MB  q  [b][H,T,HD]
        ushort* kbA = qbA + 2 * PB;            // [2] x 4 MB  k
        ushort* vtA = qbA + 4 * PB;            // [2] x 4 MB  v^T
        ushort* ybA = qbA + 6 * PB;            // [2] x 4 MB  x_bf16 / y
        ushort* wtP = qbA + 8 * PB;            // 2 MB  W_proj^T

        tp_k<<<dim3(96, 32), 256, 0, stream>>>(Wa, wtA, 1024, 3072);
        trig_k<<<dim3(256), 256, 0, stream>>>(tab);
        tp_k<<<dim3(32, 32), 256, 0, stream>>>(Wp, wtP, 1024, 1024);

        cvt_k<<<dim3(4096), 256, 0, stream>>>(x, ybA);
        gemm1_qkv_k<<<dim3(24, 16, 2), 256, 0, stream>>>(ybA, wtA, qbA, kbA, vtA);
        rope_k<<<dim3(16384), 256, 0, stream>>>(qbA, kbA, tab);
        attn_k<<<dim3(1024), 256, 0, stream>>>(qbA, kbA, vtA, ybA);
        gemm2_proj_k<<<dim3(8, 32, 2), 256, 0, stream>>>(ybA, wtP, out);
        return;
    }

    // -------- fallback: per-batch loop (same kernels, z=1 grids) ----------
    ushort* qb  = (ushort*)d_ws;               // 4 MB bf16 q
    ushort* kb  = qb + PB;                     // 4 MB bf16 k
    ushort* vtb = kb + PB;                     // 4 MB bf16 v^T
    ushort* yb  = vtb + PB;                    // 4 MB bf16 y / x_bf16
    const bool hoistWp = ws_size >= (size_t)18 * 1024 * 1024;
    ushort* wtP_stable = yb + PB;              // d_ws + 16MB (only if hoistWp)

    tp_k<<<dim3(96, 32), 256, 0, stream>>>(Wa, wtA, 1024, 3072);
    trig_k<<<dim3(256), 256, 0, stream>>>(tab);
    if (hoistWp)
        tp_k<<<dim3(32, 32), 256, 0, stream>>>(Wp, wtP_stable, 1024, 1024);

    for (int b = 0; b < 2; b++) {
        cvt_k<<<dim3(2048), 256, 0, stream>>>(x + b * PB, yb);        // xb in yb slot
        gemm1_qkv_k<<<dim3(24, 16, 1), 256, 0, stream>>>(yb, wtA, qb, kb, vtb);
        rope_k<<<dim3(8192), 256, 0, stream>>>(qb, kb, tab);
        attn_k<<<dim3(512), 256, 0, stream>>>(qb, kb, vtb, yb);       // y over xb
        if (hoistWp) {
            gemm2_proj_k<<<dim3(8, 32, 1), 256, 0, stream>>>(yb, wtP_stable, out + b * PB);
        } else {
            tp_k<<<dim3(32, 32), 256, 0, stream>>>(Wp, qb, 1024, 1024);  // over dead q
            gemm2_proj_k<<<dim3(8, 32, 1), 256, 0, stream>>>(yb, qb, out + b * PB);
        }
    }
}